// Round 12
// baseline (359.856 us; speedup 1.0000x reference)
//
#include <hip/hip_runtime.h>
#include <stdint.h>

// RNN car-following, 256 sequential steps x 4096 vehicles.
// Round-16: FIX the R15 race (absmax 8->24 was a real data race, not noise).
// R15 moved j9/j10 partials wholesale to wid2, but the dw1 tap reads P-pair
// (tau+20)%21 written at step tau-2 -- INSIDE the same superstep wid2 runs
// (chain writes steps 2k,2k+1; wid2 read races). Structural rule learned:
// 2-steps-fresh data can only be consumed by the in-order chain wave;
// helpers may take >=4-step-old work only.
// Hybrid split:
//  - wid2: j9 partial = bias + dw0 (pair tau+18, written tau-4 = prev
//    superstep, SAFE) -> JA2 ring. JB2 deleted (-16KB LDS).
//  - chain: one early ld_P(pair (t+20)) (written t-2 = prev superstep for
//    both substeps; verified) + 8 MFMA at STEP START, latency hidden under
//    the conv1 chain (results only needed at o2_write after fresh taps).
// Everything else from R15 kept (shared-column conv1, lead hoist, Jpart).
// Verification signal: absmax must return to 8.0.

#define PAST 25
#define NTW_MAX 280

typedef __attribute__((ext_vector_type(8))) short bf16x8;
typedef __attribute__((ext_vector_type(4))) float f32x4;
typedef unsigned short u16x2 __attribute__((ext_vector_type(2)));
#define MFMA16 __builtin_amdgcn_mfma_f32_16x16x32_bf16

static __device__ __forceinline__ uint32_t f2bf(float f) {
  union { float f; uint32_t u; } x; x.f = f;
  return (x.u + 0x7FFFu + ((x.u >> 16) & 1u)) >> 16;
}
static __device__ __forceinline__ float bf2f(uint32_t b) {
  union { uint32_t u; float f; } x; x.u = b << 16; return x.f;
}
// one-instruction RNE pack of two f32 -> packed bf16x2 (low=lo, high=hi)
static __device__ __forceinline__ uint32_t pkbf(float lo, float hi) {
  uint32_t r;
  asm("v_cvt_pk_bf16_f32 %0, %1, %2" : "=v"(r) : "v"(lo), "v"(hi));
  return r;
}
static __device__ __forceinline__ f32x4 bcast4(float v) { f32x4 r = {v, v, v, v}; return r; }

static __device__ __forceinline__ uint32_t pkmax(uint32_t a, uint32_t b) {
#if __has_builtin(__builtin_elementwise_max)
  union U { uint32_t w; u16x2 v; } x, y; x.w = a; y.w = b;
  x.v = __builtin_elementwise_max(x.v, y.v);
  return x.w;
#else
  uint32_t al = a << 16, bl = b << 16;
  uint32_t lo = (al > bl ? al : bl) >> 16;
  uint32_t ah = a & 0xffff0000u, bh = b & 0xffff0000u;
  uint32_t hi = ah > bh ? ah : bh;
  return lo | hi;
#endif
}
static __device__ __forceinline__ uint4 maxq(uint4 a, uint4 b) {
  uint4 r; r.x = pkmax(a.x, b.x); r.y = pkmax(a.y, b.y);
  r.z = pkmax(a.z, b.z); r.w = pkmax(a.w, b.w); return r;
}
// wraps: valid for x < 63 (w21) / x < 51 (w17)
static __device__ __forceinline__ int w21(int x) { if (x >= 21) x -= 21; if (x >= 21) x -= 21; return x; }
static __device__ __forceinline__ int w17(int x) { if (x >= 17) x -= 17; if (x >= 17) x -= 17; return x; }
// sum across each 16-lane row via DPP rotate-accumulate (row_ror 1/2/4/8).
static __device__ __forceinline__ float rsum16(float x) {
  x += __builtin_bit_cast(float, __builtin_amdgcn_update_dpp(0, __builtin_bit_cast(int, x), 0x121, 0xf, 0xf, true));
  x += __builtin_bit_cast(float, __builtin_amdgcn_update_dpp(0, __builtin_bit_cast(int, x), 0x122, 0xf, 0xf, true));
  x += __builtin_bit_cast(float, __builtin_amdgcn_update_dpp(0, __builtin_bit_cast(int, x), 0x124, 0xf, 0xf, true));
  x += __builtin_bit_cast(float, __builtin_amdgcn_update_dpp(0, __builtin_bit_cast(int, x), 0x128, 0xf, 0xf, true));
  return x;
}

union FragU { bf16x8 v; uint16_t u[8]; uint4 q; };
struct RowD { f32x4 d0, d1; };   // swapped conv1 out: lane=veh (col n), regs=ch quad*4+r

// 4224 + 16384 + 8192 + 25600 + 45056 + 8192 + 4096 + 4096 + 16384 = 132224 B
struct __align__(16) SMem {
  uint32_t Xcol[16][33][2];   // x-column ring (u&31)
  float    leadx[16][256];    // lead pos, idx = t, t in [0, ntw-26]
  uint16_t leady[16][256];    // f2bf(lead speed * 0.025)
  uint16_t P[25 * 16 * 32];   // conv1 pairs: ring 0..20 (g%21), R0 ring 21..24
  uint16_t O2[22 * 16 * 64];  // ring 0..16, J0 ring 17..20, 21 = j10 scratch
  float2 obuf[2][16][32];     // output dbuf (flushed every 32 steps)
  f32x4 JpartA[4][64];        // jp0..jp3 partial dense acc (hf=0), ring by t&3
  f32x4 JpartB[4][64];        // (hf=1)
  f32x4 JA2[4][4][64];        // j9 partial (bias+dw0 ONLY), ring by t&3, [ct][lane]
};

__global__ __launch_bounds__(256, 1) void rnncf_kernel(
    const float* __restrict__ lead_states, const float* __restrict__ cur_states,
    const float* __restrict__ conv1_w, const float* __restrict__ conv1_b,
    const float* __restrict__ conv2_w, const float* __restrict__ conv2_b,
    const float* __restrict__ dense2_w, const float* __restrict__ dense2_b,
    const float* __restrict__ dense1_w, const float* __restrict__ dense1_b,
    float* __restrict__ out, int nt, int ntw) {
  __shared__ SMem sm;
  const int tid = threadIdx.x;
  const int lane = tid & 63;
  const int wid = tid >> 6;           // 0..3
  const int n = lane & 15;
  const int quad = lane >> 4;
  const int vbase = blockIdx.x * 16;

  // ---------------- phase 0: Xcol ring + lead preload + state ----------------
  for (int i = tid; i < 16 * PAST; i += 256) {
    int v = i & 15, u = i >> 4;
    const float2 l = *(const float2*)(lead_states + ((size_t)(vbase + v) * ntw + u) * 2);
    const float2 c = *(const float2*)(cur_states + ((size_t)(vbase + v) * PAST + u) * 2);
    float x0 = (l.x - c.x) * 0.005f;
    uint32_t w0 = pkbf(x0, c.y * 0.025f);
    sm.Xcol[v][u][0] = w0;
    sm.Xcol[v][u][1] = pkbf(l.y * 0.025f, x0 - bf2f(w0 & 0xffffu));
  }
#pragma unroll
  for (int v = 0; v < 16; ++v)
    for (int i = 25 + tid; i < ntw; i += 256) {
      const float2 l = *(const float2*)(lead_states + ((size_t)(vbase + v) * ntw + i) * 2);
      sm.leadx[v][i - 25] = l.x;
      sm.leady[v][i - 25] = (uint16_t)f2bf(l.y * 0.025f);
    }

  float pos_s = 0.f, spd_s = 0.f;
  if (wid == 3 && n < 4) {            // state lives on the chain wave; 16 veh
    int veh = quad * 4 + n;
    const float2 c = *(const float2*)(cur_states + ((size_t)(vbase + veh) * PAST + 24) * 2);
    pos_s = c.x * 0.005f; spd_s = c.y * 0.025f;
  }

  // ---------------- weight fragments ----------------
  FragU B1[2];
#pragma unroll
  for (int ct = 0; ct < 2; ++ct)
#pragma unroll
    for (int jj = 0; jj < 8; ++jj) {
      int k = quad * 8 + jj;
      int dw = k & 3, cig = (k >> 2) & 3;
      float w = 0.f;
      if (k < 16 && dw < 3) {
        int ci = (cig == 3) ? 0 : cig;
        w = conv1_w[(dw * 3 + ci) * 32 + ct * 16 + n];
      }
      B1[ct].u[jj] = (uint16_t)f2bf(w);
    }
  FragU B2[3][4];
#pragma unroll
  for (int dw = 0; dw < 3; ++dw)
#pragma unroll
    for (int ct = 0; ct < 4; ++ct)
#pragma unroll
      for (int jj = 0; jj < 8; ++jj) {
        int kap = quad * 8 + jj;
        int ci = (kap & 1) * 16 + (kap >> 1);
        B2[dw][ct].u[jj] = (uint16_t)f2bf(conv2_w[(dw * 32 + ci) * 64 + ct * 16 + n]);
      }
  FragU Bd[12];
#pragma unroll
  for (int kt = 0; kt < 12; ++kt)
#pragma unroll
    for (int jj = 0; jj < 8; ++jj) {
      int flat = kt * 32 + quad * 8 + jj;
      int jp = flat >> 6, kap = flat & 63;
      int co = (kap & 3) * 16 + (kap >> 2);
      Bd[kt].u[jj] = (uint16_t)f2bf((n < 10) ? dense2_w[(jp * 64 + co) * 10 + n] : 0.f);
    }
  f32x4 b1q0, b1q1;
#pragma unroll
  for (int r = 0; r < 4; ++r) {
    b1q0[r] = conv1_b[quad * 4 + r];
    b1q1[r] = conv1_b[16 + quad * 4 + r];
  }
  float b2v[4];
#pragma unroll
  for (int ct = 0; ct < 4; ++ct) b2v[ct] = conv2_b[ct * 16 + n];
  const float d2bv = (n < 10) ? dense2_b[n] : 0.f;
  const float wd1v = (n < 10) ? dense1_w[n] : 0.f;
  const float bd1v = dense1_b[0];

  // ---------------- helpers (16-veh indexing) ----------------
  auto pIdx = [&](int s, int veh, int ch) { return ((s * 16 + veh) * 4 + ch) * 8; };
  auto oIdx = [&](int s, int veh, int ch) { return ((s * 16 + veh) * 8 + ch) * 8; };

  auto build_x = [&](int c, int padL, int padR) -> FragU {
    int h = quad & 1, v8 = n;
    uint32_t d0 = padL ? 0u : sm.Xcol[v8][(c - 1) & 31][h];
    uint32_t d1 = sm.Xcol[v8][c & 31][h];
    uint32_t d2 = padR ? 0u : sm.Xcol[v8][(c + 1) & 31][h];
    FragU a;
    a.q.x = __builtin_amdgcn_perm(d1, d0, 0x05040100u);
    a.q.y = d2 & 0xffffu;
    a.q.z = __builtin_amdgcn_perm(d1, d0, 0x07060302u);
    a.q.w = d2 >> 16;
    return a;
  };

  auto conv1s_row = [&](int c, int padL, int padR) -> RowD {
    FragU a = build_x(c, padL, padR);
    RowD rd;
    rd.d0 = MFMA16(B1[0].v, a.v, b1q0, 0, 0, 0);
    rd.d1 = MFMA16(B1[1].v, a.v, b1q1, 0, 0, 0);
    return rd;
  };

  auto relumax4 = [&](const f32x4& a, const f32x4& b) -> f32x4 {
    f32x4 r;
#pragma unroll
    for (int i = 0; i < 4; ++i) r[i] = fmaxf(fmaxf(a[i], b[i]), 0.f);
    return r;
  };
  auto relu4 = [&](const f32x4& a) -> f32x4 {
    f32x4 r;
#pragma unroll
    for (int i = 0; i < 4; ++i) r[i] = fmaxf(a[i], 0.f);
    return r;
  };
  auto pack4 = [&](const f32x4& p0, const f32x4& p1) -> uint4 {
    uint4 w;
    w.x = pkbf(p0[0], p1[0]); w.y = pkbf(p0[1], p1[1]);
    w.z = pkbf(p0[2], p1[2]); w.w = pkbf(p0[3], p1[3]);
    return w;
  };
  auto p_store = [&](const uint4& w, int ds) {
    *(uint4*)&sm.P[pIdx(ds, n, quad ^ (n & 3))] = w;
  };
  auto pool_store = [&](const RowD& A, const RowD& Bq, int ds) {
    p_store(pack4(relumax4(A.d0, Bq.d0), relumax4(A.d1, Bq.d1)), ds);
  };

  auto ld_P = [&](int s) -> FragU {
    FragU a; a.q = *(const uint4*)&sm.P[pIdx(s, n, quad ^ (n & 3))]; return a;
  };

  auto conv2_acc = [&](f32x4* acc, int slot, int dw) {
    FragU a = ld_P(slot);
#pragma unroll
    for (int ct = 0; ct < 4; ++ct) acc[ct] = MFMA16(a.v, B2[dw][ct].v, acc[ct], 0, 0, 0);
  };

  auto conv2_accf = [&](f32x4* acc, const FragU& a, int dw) {
#pragma unroll
    for (int ct = 0; ct < 4; ++ct) acc[ct] = MFMA16(a.v, B2[dw][ct].v, acc[ct], 0, 0, 0);
  };

  auto o2_write = [&](const f32x4* acc, int ds) {
#pragma unroll
    for (int r = 0; r < 4; ++r) {
      int veh = quad * 4 + r;
      float m0 = fmaxf(acc[0][r], 0.f), m1 = fmaxf(acc[1][r], 0.f);
      float m2 = fmaxf(acc[2][r], 0.f), m3 = fmaxf(acc[3][r], 0.f);
      uint2 w2; w2.x = pkbf(m0, m1); w2.y = pkbf(m2, m3);
      *(uint2*)&sm.O2[oIdx(ds, veh, (n >> 1) ^ (veh & 7)) + (n & 1) * 4] = w2;
    }
  };

  auto dense_jp = [&](int pa, int pb, int jp, f32x4& a0, f32x4& a1) {
#pragma unroll
    for (int hf = 0; hf < 2; ++hf) {
      uint4 qa = *(const uint4*)&sm.O2[oIdx(pa, n, (hf * 4 + quad) ^ (n & 7))];
      if (pb >= 0) {
        uint4 qb = *(const uint4*)&sm.O2[oIdx(pb, n, (hf * 4 + quad) ^ (n & 7))];
        qa = maxq(qa, qb);
      }
      FragU a; a.q = qa;
      if (hf == 0) a0 = MFMA16(a.v, Bd[jp * 2].v, a0, 0, 0, 0);
      else         a1 = MFMA16(a.v, Bd[jp * 2 + 1].v, a1, 0, 0, 0);
    }
  };

  auto dense_jp_pre = [&](int pa, const uint4* qpre, int jp, f32x4& a0, f32x4& a1) {
#pragma unroll
    for (int hf = 0; hf < 2; ++hf) {
      uint4 qa = *(const uint4*)&sm.O2[oIdx(pa, n, (hf * 4 + quad) ^ (n & 7))];
      if (qpre) qa = maxq(qa, qpre[hf]);
      FragU a; a.q = qa;
      if (hf == 0) a0 = MFMA16(a.v, Bd[jp * 2].v, a0, 0, 0, 0);
      else         a1 = MFMA16(a.v, Bd[jp * 2 + 1].v, a1, 0, 0, 0);
    }
  };

  auto flush_out = [&](int bi, int t0, int cnt) {
    int vv = lane >> 2;
    int s0 = (lane & 3) * 8;
#pragma unroll
    for (int kk = 0; kk < 8; ++kk) {
      int s = s0 + kk;
      if (s < cnt) {
        float2 d = sm.obuf[bi][vv][s];
        *(float2*)(out + ((size_t)(vbase + vv) * nt + t0 + s) * 2) = d;
      }
    }
  };

  // j9 partial (bias + dw0 ONLY; pair tau+18 is >=1 superstep old -- SAFE)
  auto j9_partial = [&](int ring, int pairA) {
    f32x4 aA[4];
#pragma unroll
    for (int ct = 0; ct < 4; ++ct) aA[ct] = bcast4(b2v[ct]);
    conv2_acc(aA, pairA, 0);
#pragma unroll
    for (int ct = 0; ct < 4; ++ct) sm.JA2[ring][ct][lane] = aA[ct];
  };

  __syncthreads();

  // ---------------- phase 1: P ring init pairs g=2..21 ----------------
#pragma unroll
  for (int i = 0; i < 5; ++i) {
    int g = 2 + wid + 4 * i;
    RowD A = conv1s_row(g, 0, 0);
    RowD Bq = conv1s_row(g + 1, 0, 0);
    pool_store(A, Bq, g % 21);
  }
  __syncthreads();

  // ---------------- phase 2: O2 ring init a=2..17 ----------------
#pragma unroll
  for (int i = 0; i < 4; ++i) {
    int a = 2 + wid + 4 * i;
    f32x4 acc[4];
#pragma unroll
    for (int ct = 0; ct < 4; ++ct) acc[ct] = bcast4(b2v[ct]);
    conv2_acc(acc, a % 21, 0);
    conv2_acc(acc, (a + 2) % 21, 1);
    conv2_acc(acc, (a + 4) % 21, 2);
    o2_write(acc, a % 17);
  }
  __syncthreads();

  // ---------------- prologue ----------------
  RowD c1A = {};
  // ProA: R0(0)->P23, R0(1)->P24
  if (wid == 0) {
    RowD A = conv1s_row(0, 1, 0), Bq = conv1s_row(1, 0, 0);
    pool_store(A, Bq, 23);
  } else if (wid == 1) {
    RowD A = conv1s_row(1, 1, 0), Bq = conv1s_row(2, 0, 0);
    pool_store(A, Bq, 24);
  }
  __syncthreads();
  // ProB: j0(0)->O2[17], j0(1)->O2[18], R0(4)->P21, R0(5)->P22
  if (wid == 0) {
    f32x4 aj[4];
#pragma unroll
    for (int ct = 0; ct < 4; ++ct) aj[ct] = bcast4(b2v[ct]);
    conv2_acc(aj, 23, 0); conv2_acc(aj, 2, 1); conv2_acc(aj, 4, 2);
    o2_write(aj, 17);
  } else if (wid == 1) {
    f32x4 aj[4];
#pragma unroll
    for (int ct = 0; ct < 4; ++ct) aj[ct] = bcast4(b2v[ct]);
    conv2_acc(aj, 24, 0); conv2_acc(aj, 3, 1); conv2_acc(aj, 5, 2);
    o2_write(aj, 18);
  } else if (wid == 2) {
    RowD A = conv1s_row(4, 1, 0), Bq = conv1s_row(5, 0, 0);
    pool_store(A, Bq, 21);
  } else {
    RowD A = conv1s_row(5, 1, 0), Bq = conv1s_row(6, 0, 0);
    pool_store(A, Bq, 22);
  }
  __syncthreads();
  // ProC: Jpart(0)->Jp[0], Jpart(1)->Jp[1], R0(2)->P23, R0(3)->P24
  if (wid == 0) {
    f32x4 a0 = bcast4(d2bv), a1 = bcast4(0.f);
    dense_jp(17, 2, 0, a0, a1);
    dense_jp(4, 6, 1, a0, a1);
    dense_jp(8, 10, 2, a0, a1);
    dense_jp(12, 14, 3, a0, a1);
    sm.JpartA[0][lane] = a0; sm.JpartB[0][lane] = a1;
  } else if (wid == 1) {
    f32x4 a0 = bcast4(d2bv), a1 = bcast4(0.f);
    dense_jp(18, 3, 0, a0, a1);
    dense_jp(5, 7, 1, a0, a1);
    dense_jp(9, 11, 2, a0, a1);
    dense_jp(13, 15, 3, a0, a1);
    sm.JpartA[1][lane] = a0; sm.JpartB[1][lane] = a1;
  } else if (wid == 2) {
    RowD A = conv1s_row(2, 1, 0), Bq = conv1s_row(3, 0, 0);
    pool_store(A, Bq, 23);
  } else {
    RowD A = conv1s_row(3, 1, 0), Bq = conv1s_row(4, 0, 0);
    pool_store(A, Bq, 24);
  }
  __syncthreads();
  // ProD: j0(2)->O2[19], j0(3)->O2[20], j9 partials(0,1), chain c1A
  if (wid == 0) {
    f32x4 aj[4];
#pragma unroll
    for (int ct = 0; ct < 4; ++ct) aj[ct] = bcast4(b2v[ct]);
    conv2_acc(aj, 23, 0); conv2_acc(aj, 4, 1); conv2_acc(aj, 6, 2);
    o2_write(aj, 19);
  } else if (wid == 1) {
    f32x4 aj[4];
#pragma unroll
    for (int ct = 0; ct < 4; ++ct) aj[ct] = bcast4(b2v[ct]);
    conv2_acc(aj, 24, 0); conv2_acc(aj, 5, 1); conv2_acc(aj, 7, 2);
    o2_write(aj, 20);
  } else if (wid == 2) {
    j9_partial(0, 18);                 // tau=0: pair (0+18)%21 = 18
    j9_partial(1, 19);                 // tau=1: pair 19
  } else {
    c1A = conv1s_row(22, 0, 0);
  }
  __syncthreads();

  if (wid == 3) __builtin_amdgcn_s_setprio(2);

  // ---------------- supersteps: 2 model steps per barrier ----------------
  int tmA21 = 0, tmA17 = 0;     // (2k)%21, (2k)%17
  const int nsup = nt >> 1;     // nt is even (256)
  for (int k = 0; k < nsup; ++k) {
    if (wid == 3) {
#pragma unroll
      for (int d = 0; d < 2; ++d) {
        const int t = 2 * k + d;
        const int sP22 = w21(tmA21 + d + 22);
        const int sO16 = w17(tmA17 + d + 16);
        const int sO18 = w17(tmA17 + d + 18);
        const int sP20 = w21(tmA21 + d + 20);   // pair (t+20): written t-2 = PREV superstep (safe)
        // ---- early off-chain loads (latency hidden under conv1) ----
        f32x4 jpA = sm.JpartA[t & 3][lane];
        f32x4 jpB = sm.JpartB[t & 3][lane];
        f32x4 pA[4];                            // j9 partial (bias+dw0) from wid2
#pragma unroll
        for (int ct = 0; ct < 4; ++ct) pA[ct] = sm.JA2[t & 3][ct][lane];
        FragU fA20 = ld_P(sP20);
        uint4 qj8[2];
#pragma unroll
        for (int hf = 0; hf < 2; ++hf)
          qj8[hf] = *(const uint4*)&sm.O2[oIdx(sO16, n, (hf * 4 + quad) ^ (n & 7))];
        // lead prefetch (ON the loop-carried path; hoisted)
        int li = t; if (li > ntw - 26) li = ntw - 26;
        float lnx = 0.f, lny = 0.f;
        if (n < 4) {
          int veh = quad * 4 + n;
          lnx = sm.leadx[veh][li];
          lny = bf2f(sm.leady[veh][li]);
        }
        // ---- finish partials through dw1 (8 MFMA, no fresh deps; issued
        //      early so latency hides under conv1) ----
        f32x4 pB[4];
#pragma unroll
        for (int ct = 0; ct < 4; ++ct) pB[ct] = bcast4(b2v[ct]);
        conv2_accf(pA, fA20, 1);                // j9 += dw1 tap
        conv2_accf(pB, fA20, 0);                // j10 = bias + dw0 tap
        // ---- fresh conv1 (shared columns t+22..t+24; Sg is padR) ----
        {
          int h = quad & 1;
          uint32_t d22 = sm.Xcol[n][(t + 22) & 31][h];
          uint32_t d23 = sm.Xcol[n][(t + 23) & 31][h];
          uint32_t d24 = sm.Xcol[n][(t + 24) & 31][h];
          FragU aB, aS;
          aB.q.x = __builtin_amdgcn_perm(d23, d22, 0x05040100u);
          aB.q.y = d24 & 0xffffu;
          aB.q.z = __builtin_amdgcn_perm(d23, d22, 0x07060302u);
          aB.q.w = d24 >> 16;
          aS.q.x = __builtin_amdgcn_perm(d24, d23, 0x05040100u);
          aS.q.y = 0u;
          aS.q.z = __builtin_amdgcn_perm(d24, d23, 0x07060302u);
          aS.q.w = 0u;
          RowD Bq, Sg;
          Bq.d0 = MFMA16(B1[0].v, aB.v, b1q0, 0, 0, 0);
          Bq.d1 = MFMA16(B1[1].v, aB.v, b1q1, 0, 0, 0);
          Sg.d0 = MFMA16(B1[0].v, aS.v, b1q0, 0, 0, 0);
          Sg.d1 = MFMA16(B1[1].v, aS.v, b1q1, 0, 0, 0);
          uint4 w11 = pack4(relumax4(c1A.d0, Bq.d0), relumax4(c1A.d1, Bq.d1));
          uint4 w12 = pack4(relu4(Sg.d0), relu4(Sg.d1));
          p_store(w11, sP22);
          c1A = Bq;
          FragU f11; f11.q = w11;               // identity: own lane's frag
          FragU f12; f12.q = w12;
          conv2_accf(pA, f11, 2);               // j9 complete
          conv2_accf(pB, f11, 1);
          conv2_accf(pB, f12, 2);               // j10 complete
          o2_write(pA, sO18);                   // j9 -> ring
          o2_write(pB, 21);                     // j10 -> scratch 21
        }
        // ---- dense + reduce + state (DS in-order covers write->read) ----
        f32x4 acc2 = bcast4(0.f), acc3 = bcast4(0.f);
        f32x4 acc4 = bcast4(0.f), acc5 = bcast4(0.f);
        dense_jp_pre(sO18, qj8, 4, acc2, acc3);
        dense_jp_pre(21, (const uint4*)nullptr, 5, acc4, acc5);
        float s0 = fmaxf(jpA[0] + jpB[0] + acc2[0] + acc3[0] + acc4[0] + acc5[0], 0.f) * wd1v;
        float s1 = fmaxf(jpA[1] + jpB[1] + acc2[1] + acc3[1] + acc4[1] + acc5[1], 0.f) * wd1v;
        float s2 = fmaxf(jpA[2] + jpB[2] + acc2[2] + acc3[2] + acc4[2] + acc5[2], 0.f) * wd1v;
        float s3 = fmaxf(jpA[3] + jpB[3] + acc2[3] + acc3[3] + acc4[3] + acc5[3], 0.f) * wd1v;
        s0 = rsum16(s0); s1 = rsum16(s1); s2 = rsum16(s2); s3 = rsum16(s3);
        if (n < 4) {
          int veh = quad * 4 + n;
          float sv = (n == 0) ? s0 : (n == 1) ? s1 : (n == 2) ? s2 : s3;
          float accv = 10.f * (sv + bd1v) - 6.f;
          float np_s = pos_s + 0.02f * spd_s;
          float nsp = spd_s * 40.f + 0.1f * accv;
          pos_s = np_s; spd_s = nsp * 0.025f;
          float2 o2v; o2v.x = np_s * 200.f; o2v.y = nsp;
          sm.obuf[(t >> 5) & 1][veh][t & 31] = o2v;
          float x0 = lnx * 0.005f - np_s;
          uint32_t wlo = pkbf(x0, spd_s);
          sm.Xcol[veh][(t + PAST) & 31][0] = wlo;
          sm.Xcol[veh][(t + PAST) & 31][1] = pkbf(lny, x0 - bf2f(wlo & 0xffffu));
        }
      }
    } else if (wid == 0) {
      // Jpart(2k+2), Jpart(2k+3)
#pragma unroll
      for (int e = 0; e < 2; ++e) {
        const int tau = 2 * k + 2 + e;
        f32x4 a0 = bcast4(d2bv), a1 = bcast4(0.f);
        dense_jp(17 + (tau & 3), w17(tmA17 + 4 + e), 0, a0, a1);     // jp0 = max(j0, j1)
        dense_jp(w17(tmA17 + 6 + e), w17(tmA17 + 8 + e), 1, a0, a1);
        dense_jp(w17(tmA17 + 10 + e), w17(tmA17 + 12 + e), 2, a0, a1);
        dense_jp(w17(tmA17 + 14 + e), w17(tmA17 + 16 + e), 3, a0, a1);
        sm.JpartA[tau & 3][lane] = a0;
        sm.JpartB[tau & 3][lane] = a1;
      }
    } else if (wid == 1) {
      // obuf flush (32-step blocks) + j0(2k+4), j0(2k+5)
      if ((k & 15) == 0 && k > 0) {
        int t0 = 2 * k - 32;
        flush_out((t0 >> 5) & 1, t0, 32);
      }
#pragma unroll
      for (int e = 0; e < 2; ++e) {
        const int tau = 2 * k + 4 + e;
        f32x4 aj[4];
#pragma unroll
        for (int ct = 0; ct < 4; ++ct) aj[ct] = bcast4(b2v[ct]);
        conv2_acc(aj, 21 + (tau & 3), 0);                 // R0(tau)
        conv2_acc(aj, w21(tmA21 + 6 + e), 1);             // pair tau+2
        conv2_acc(aj, w21(tmA21 + 8 + e), 2);             // pair tau+4
        o2_write(aj, 17 + (tau & 3));                     // J0[tau&3]
      }
    } else {
      // j9 partials(2k+2, 2k+3) [dw0 only, safe] + row0(2k+6), row0(2k+7)
#pragma unroll
      for (int e = 0; e < 2; ++e) {
        const int tau = 2 * k + 2 + e;
        j9_partial(tau & 3, w21(tmA21 + 20 + e));         // pair tau+18
      }
#pragma unroll
      for (int f = 0; f < 2; ++f) {
        const int tau = 2 * k + 6 + f;
        RowD A = conv1s_row(tau, 1, 0);
        RowD Bq = conv1s_row(tau + 1, 0, 0);
        pool_store(A, Bq, 21 + (tau & 3));
      }
    }
    __syncthreads();
    tmA21 = w21(tmA21 + 2);
    tmA17 = w17(tmA17 + 2);
  }

  // final output flush (steps [nt-32, nt-1])
  if (wid == 1) {
    int t0 = (nt - 1) & ~31;
    flush_out((t0 >> 5) & 1, t0, nt - t0);
  }
}

extern "C" void kernel_launch(void* const* d_in, const int* in_sizes, int n_in,
                              void* d_out, int out_size, void* d_ws, size_t ws_size,
                              hipStream_t stream) {
  const float* lead = (const float*)d_in[0];
  const float* cur  = (const float*)d_in[1];
  // d_in[2] = mask (unused by reference)
  const float* c1w = (const float*)d_in[3];
  const float* c1b = (const float*)d_in[4];
  const float* c2w = (const float*)d_in[5];
  const float* c2b = (const float*)d_in[6];
  const float* d2w = (const float*)d_in[7];
  const float* d2b = (const float*)d_in[8];
  const float* d1w = (const float*)d_in[9];
  const float* d1b = (const float*)d_in[10];
  float* out = (float*)d_out;

  int nveh = in_sizes[1] / (PAST * 2);   // 4096
  int ntw  = in_sizes[2] / nveh;         // nt + PAST - 1 (<= NTW_MAX)
  int nt   = ntw - PAST + 1;             // 256 (even)
  int nblocks = nveh / 16;               // 256 = one per CU

  rnncf_kernel<<<nblocks, 256, 0, stream>>>(lead, cur, c1w, c1b, c2w, c2b,
                                            d2w, d2b, d1w, d1b, out, nt, ntw);
}

// Round 13
// 353.138 us; speedup vs baseline: 1.0190x; 1.0190x over previous
//
#include <hip/hip_runtime.h>
#include <stdint.h>

// RNN car-following, 256 sequential steps x 4096 vehicles.
// Round-17: CRITICAL-FIRST ISSUE ORDER on the chain. R16 post-mortem: LDS
// returns are IN-ORDER per wave; R16 issued 9 off-chain reads then 8 MFMA
// that consume load #7 -> near-full lgkmcnt drain + MFMA stall BEFORE the
// loop-carried Xcol reads even issued. Fix (same work, same safety):
//   1. Xcol d22/d23/d24 reads issue FIRST (queue pos 1-3),
//   2. off-chain loads (Jpart, JA2, fA20, qj8, lead) issue behind them,
//   3. conv1 waits only for the first 3 returns (counted lgkmcnt),
//   4. partial-finish MFMAs run after conv1 (their loads drained under it),
//   5. fresh taps -> o2_write -> dense -> epilogue unchanged.
// R16's race fix retained: helpers only touch >=4-step-old pairs; the
// 2-step-fresh dw1/j10-dw0 tap stays on the in-order chain wave.
// Verification: absmax must stay 8.0; FETCH ~5.36MB (spill tripwire).

#define PAST 25
#define NTW_MAX 280

typedef __attribute__((ext_vector_type(8))) short bf16x8;
typedef __attribute__((ext_vector_type(4))) float f32x4;
typedef unsigned short u16x2 __attribute__((ext_vector_type(2)));
#define MFMA16 __builtin_amdgcn_mfma_f32_16x16x32_bf16

static __device__ __forceinline__ uint32_t f2bf(float f) {
  union { float f; uint32_t u; } x; x.f = f;
  return (x.u + 0x7FFFu + ((x.u >> 16) & 1u)) >> 16;
}
static __device__ __forceinline__ float bf2f(uint32_t b) {
  union { uint32_t u; float f; } x; x.u = b << 16; return x.f;
}
// one-instruction RNE pack of two f32 -> packed bf16x2 (low=lo, high=hi)
static __device__ __forceinline__ uint32_t pkbf(float lo, float hi) {
  uint32_t r;
  asm("v_cvt_pk_bf16_f32 %0, %1, %2" : "=v"(r) : "v"(lo), "v"(hi));
  return r;
}
static __device__ __forceinline__ f32x4 bcast4(float v) { f32x4 r = {v, v, v, v}; return r; }

static __device__ __forceinline__ uint32_t pkmax(uint32_t a, uint32_t b) {
#if __has_builtin(__builtin_elementwise_max)
  union U { uint32_t w; u16x2 v; } x, y; x.w = a; y.w = b;
  x.v = __builtin_elementwise_max(x.v, y.v);
  return x.w;
#else
  uint32_t al = a << 16, bl = b << 16;
  uint32_t lo = (al > bl ? al : bl) >> 16;
  uint32_t ah = a & 0xffff0000u, bh = b & 0xffff0000u;
  uint32_t hi = ah > bh ? ah : bh;
  return lo | hi;
#endif
}
static __device__ __forceinline__ uint4 maxq(uint4 a, uint4 b) {
  uint4 r; r.x = pkmax(a.x, b.x); r.y = pkmax(a.y, b.y);
  r.z = pkmax(a.z, b.z); r.w = pkmax(a.w, b.w); return r;
}
// wraps: valid for x < 63 (w21) / x < 51 (w17)
static __device__ __forceinline__ int w21(int x) { if (x >= 21) x -= 21; if (x >= 21) x -= 21; return x; }
static __device__ __forceinline__ int w17(int x) { if (x >= 17) x -= 17; if (x >= 17) x -= 17; return x; }
// sum across each 16-lane row via DPP rotate-accumulate (row_ror 1/2/4/8).
static __device__ __forceinline__ float rsum16(float x) {
  x += __builtin_bit_cast(float, __builtin_amdgcn_update_dpp(0, __builtin_bit_cast(int, x), 0x121, 0xf, 0xf, true));
  x += __builtin_bit_cast(float, __builtin_amdgcn_update_dpp(0, __builtin_bit_cast(int, x), 0x122, 0xf, 0xf, true));
  x += __builtin_bit_cast(float, __builtin_amdgcn_update_dpp(0, __builtin_bit_cast(int, x), 0x124, 0xf, 0xf, true));
  x += __builtin_bit_cast(float, __builtin_amdgcn_update_dpp(0, __builtin_bit_cast(int, x), 0x128, 0xf, 0xf, true));
  return x;
}

union FragU { bf16x8 v; uint16_t u[8]; uint4 q; };
struct RowD { f32x4 d0, d1; };   // swapped conv1 out: lane=veh (col n), regs=ch quad*4+r

// 4224 + 16384 + 8192 + 25600 + 45056 + 8192 + 4096 + 4096 + 16384 = 132224 B
struct __align__(16) SMem {
  uint32_t Xcol[16][33][2];   // x-column ring (u&31)
  float    leadx[16][256];    // lead pos, idx = t, t in [0, ntw-26]
  uint16_t leady[16][256];    // f2bf(lead speed * 0.025)
  uint16_t P[25 * 16 * 32];   // conv1 pairs: ring 0..20 (g%21), R0 ring 21..24
  uint16_t O2[22 * 16 * 64];  // ring 0..16, J0 ring 17..20, 21 = j10 scratch
  float2 obuf[2][16][32];     // output dbuf (flushed every 32 steps)
  f32x4 JpartA[4][64];        // jp0..jp3 partial dense acc (hf=0), ring by t&3
  f32x4 JpartB[4][64];        // (hf=1)
  f32x4 JA2[4][4][64];        // j9 partial (bias+dw0 ONLY), ring by t&3, [ct][lane]
};

__global__ __launch_bounds__(256, 1) void rnncf_kernel(
    const float* __restrict__ lead_states, const float* __restrict__ cur_states,
    const float* __restrict__ conv1_w, const float* __restrict__ conv1_b,
    const float* __restrict__ conv2_w, const float* __restrict__ conv2_b,
    const float* __restrict__ dense2_w, const float* __restrict__ dense2_b,
    const float* __restrict__ dense1_w, const float* __restrict__ dense1_b,
    float* __restrict__ out, int nt, int ntw) {
  __shared__ SMem sm;
  const int tid = threadIdx.x;
  const int lane = tid & 63;
  const int wid = tid >> 6;           // 0..3
  const int n = lane & 15;
  const int quad = lane >> 4;
  const int vbase = blockIdx.x * 16;

  // ---------------- phase 0: Xcol ring + lead preload + state ----------------
  for (int i = tid; i < 16 * PAST; i += 256) {
    int v = i & 15, u = i >> 4;
    const float2 l = *(const float2*)(lead_states + ((size_t)(vbase + v) * ntw + u) * 2);
    const float2 c = *(const float2*)(cur_states + ((size_t)(vbase + v) * PAST + u) * 2);
    float x0 = (l.x - c.x) * 0.005f;
    uint32_t w0 = pkbf(x0, c.y * 0.025f);
    sm.Xcol[v][u][0] = w0;
    sm.Xcol[v][u][1] = pkbf(l.y * 0.025f, x0 - bf2f(w0 & 0xffffu));
  }
#pragma unroll
  for (int v = 0; v < 16; ++v)
    for (int i = 25 + tid; i < ntw; i += 256) {
      const float2 l = *(const float2*)(lead_states + ((size_t)(vbase + v) * ntw + i) * 2);
      sm.leadx[v][i - 25] = l.x;
      sm.leady[v][i - 25] = (uint16_t)f2bf(l.y * 0.025f);
    }

  float pos_s = 0.f, spd_s = 0.f;
  if (wid == 3 && n < 4) {            // state lives on the chain wave; 16 veh
    int veh = quad * 4 + n;
    const float2 c = *(const float2*)(cur_states + ((size_t)(vbase + veh) * PAST + 24) * 2);
    pos_s = c.x * 0.005f; spd_s = c.y * 0.025f;
  }

  // ---------------- weight fragments ----------------
  FragU B1[2];
#pragma unroll
  for (int ct = 0; ct < 2; ++ct)
#pragma unroll
    for (int jj = 0; jj < 8; ++jj) {
      int k = quad * 8 + jj;
      int dw = k & 3, cig = (k >> 2) & 3;
      float w = 0.f;
      if (k < 16 && dw < 3) {
        int ci = (cig == 3) ? 0 : cig;
        w = conv1_w[(dw * 3 + ci) * 32 + ct * 16 + n];
      }
      B1[ct].u[jj] = (uint16_t)f2bf(w);
    }
  FragU B2[3][4];
#pragma unroll
  for (int dw = 0; dw < 3; ++dw)
#pragma unroll
    for (int ct = 0; ct < 4; ++ct)
#pragma unroll
      for (int jj = 0; jj < 8; ++jj) {
        int kap = quad * 8 + jj;
        int ci = (kap & 1) * 16 + (kap >> 1);
        B2[dw][ct].u[jj] = (uint16_t)f2bf(conv2_w[(dw * 32 + ci) * 64 + ct * 16 + n]);
      }
  FragU Bd[12];
#pragma unroll
  for (int kt = 0; kt < 12; ++kt)
#pragma unroll
    for (int jj = 0; jj < 8; ++jj) {
      int flat = kt * 32 + quad * 8 + jj;
      int jp = flat >> 6, kap = flat & 63;
      int co = (kap & 3) * 16 + (kap >> 2);
      Bd[kt].u[jj] = (uint16_t)f2bf((n < 10) ? dense2_w[(jp * 64 + co) * 10 + n] : 0.f);
    }
  f32x4 b1q0, b1q1;
#pragma unroll
  for (int r = 0; r < 4; ++r) {
    b1q0[r] = conv1_b[quad * 4 + r];
    b1q1[r] = conv1_b[16 + quad * 4 + r];
  }
  float b2v[4];
#pragma unroll
  for (int ct = 0; ct < 4; ++ct) b2v[ct] = conv2_b[ct * 16 + n];
  const float d2bv = (n < 10) ? dense2_b[n] : 0.f;
  const float wd1v = (n < 10) ? dense1_w[n] : 0.f;
  const float bd1v = dense1_b[0];

  // ---------------- helpers (16-veh indexing) ----------------
  auto pIdx = [&](int s, int veh, int ch) { return ((s * 16 + veh) * 4 + ch) * 8; };
  auto oIdx = [&](int s, int veh, int ch) { return ((s * 16 + veh) * 8 + ch) * 8; };

  auto build_x = [&](int c, int padL, int padR) -> FragU {
    int h = quad & 1, v8 = n;
    uint32_t d0 = padL ? 0u : sm.Xcol[v8][(c - 1) & 31][h];
    uint32_t d1 = sm.Xcol[v8][c & 31][h];
    uint32_t d2 = padR ? 0u : sm.Xcol[v8][(c + 1) & 31][h];
    FragU a;
    a.q.x = __builtin_amdgcn_perm(d1, d0, 0x05040100u);
    a.q.y = d2 & 0xffffu;
    a.q.z = __builtin_amdgcn_perm(d1, d0, 0x07060302u);
    a.q.w = d2 >> 16;
    return a;
  };

  auto conv1s_row = [&](int c, int padL, int padR) -> RowD {
    FragU a = build_x(c, padL, padR);
    RowD rd;
    rd.d0 = MFMA16(B1[0].v, a.v, b1q0, 0, 0, 0);
    rd.d1 = MFMA16(B1[1].v, a.v, b1q1, 0, 0, 0);
    return rd;
  };

  auto relumax4 = [&](const f32x4& a, const f32x4& b) -> f32x4 {
    f32x4 r;
#pragma unroll
    for (int i = 0; i < 4; ++i) r[i] = fmaxf(fmaxf(a[i], b[i]), 0.f);
    return r;
  };
  auto relu4 = [&](const f32x4& a) -> f32x4 {
    f32x4 r;
#pragma unroll
    for (int i = 0; i < 4; ++i) r[i] = fmaxf(a[i], 0.f);
    return r;
  };
  auto pack4 = [&](const f32x4& p0, const f32x4& p1) -> uint4 {
    uint4 w;
    w.x = pkbf(p0[0], p1[0]); w.y = pkbf(p0[1], p1[1]);
    w.z = pkbf(p0[2], p1[2]); w.w = pkbf(p0[3], p1[3]);
    return w;
  };
  auto p_store = [&](const uint4& w, int ds) {
    *(uint4*)&sm.P[pIdx(ds, n, quad ^ (n & 3))] = w;
  };
  auto pool_store = [&](const RowD& A, const RowD& Bq, int ds) {
    p_store(pack4(relumax4(A.d0, Bq.d0), relumax4(A.d1, Bq.d1)), ds);
  };

  auto ld_P = [&](int s) -> FragU {
    FragU a; a.q = *(const uint4*)&sm.P[pIdx(s, n, quad ^ (n & 3))]; return a;
  };

  auto conv2_acc = [&](f32x4* acc, int slot, int dw) {
    FragU a = ld_P(slot);
#pragma unroll
    for (int ct = 0; ct < 4; ++ct) acc[ct] = MFMA16(a.v, B2[dw][ct].v, acc[ct], 0, 0, 0);
  };

  auto conv2_accf = [&](f32x4* acc, const FragU& a, int dw) {
#pragma unroll
    for (int ct = 0; ct < 4; ++ct) acc[ct] = MFMA16(a.v, B2[dw][ct].v, acc[ct], 0, 0, 0);
  };

  auto o2_write = [&](const f32x4* acc, int ds) {
#pragma unroll
    for (int r = 0; r < 4; ++r) {
      int veh = quad * 4 + r;
      float m0 = fmaxf(acc[0][r], 0.f), m1 = fmaxf(acc[1][r], 0.f);
      float m2 = fmaxf(acc[2][r], 0.f), m3 = fmaxf(acc[3][r], 0.f);
      uint2 w2; w2.x = pkbf(m0, m1); w2.y = pkbf(m2, m3);
      *(uint2*)&sm.O2[oIdx(ds, veh, (n >> 1) ^ (veh & 7)) + (n & 1) * 4] = w2;
    }
  };

  auto dense_jp = [&](int pa, int pb, int jp, f32x4& a0, f32x4& a1) {
#pragma unroll
    for (int hf = 0; hf < 2; ++hf) {
      uint4 qa = *(const uint4*)&sm.O2[oIdx(pa, n, (hf * 4 + quad) ^ (n & 7))];
      if (pb >= 0) {
        uint4 qb = *(const uint4*)&sm.O2[oIdx(pb, n, (hf * 4 + quad) ^ (n & 7))];
        qa = maxq(qa, qb);
      }
      FragU a; a.q = qa;
      if (hf == 0) a0 = MFMA16(a.v, Bd[jp * 2].v, a0, 0, 0, 0);
      else         a1 = MFMA16(a.v, Bd[jp * 2 + 1].v, a1, 0, 0, 0);
    }
  };

  auto dense_jp_pre = [&](int pa, const uint4* qpre, int jp, f32x4& a0, f32x4& a1) {
#pragma unroll
    for (int hf = 0; hf < 2; ++hf) {
      uint4 qa = *(const uint4*)&sm.O2[oIdx(pa, n, (hf * 4 + quad) ^ (n & 7))];
      if (qpre) qa = maxq(qa, qpre[hf]);
      FragU a; a.q = qa;
      if (hf == 0) a0 = MFMA16(a.v, Bd[jp * 2].v, a0, 0, 0, 0);
      else         a1 = MFMA16(a.v, Bd[jp * 2 + 1].v, a1, 0, 0, 0);
    }
  };

  auto flush_out = [&](int bi, int t0, int cnt) {
    int vv = lane >> 2;
    int s0 = (lane & 3) * 8;
#pragma unroll
    for (int kk = 0; kk < 8; ++kk) {
      int s = s0 + kk;
      if (s < cnt) {
        float2 d = sm.obuf[bi][vv][s];
        *(float2*)(out + ((size_t)(vbase + vv) * nt + t0 + s) * 2) = d;
      }
    }
  };

  // j9 partial (bias + dw0 ONLY; pair tau+18 is >=1 superstep old -- SAFE)
  auto j9_partial = [&](int ring, int pairA) {
    f32x4 aA[4];
#pragma unroll
    for (int ct = 0; ct < 4; ++ct) aA[ct] = bcast4(b2v[ct]);
    conv2_acc(aA, pairA, 0);
#pragma unroll
    for (int ct = 0; ct < 4; ++ct) sm.JA2[ring][ct][lane] = aA[ct];
  };

  __syncthreads();

  // ---------------- phase 1: P ring init pairs g=2..21 ----------------
#pragma unroll
  for (int i = 0; i < 5; ++i) {
    int g = 2 + wid + 4 * i;
    RowD A = conv1s_row(g, 0, 0);
    RowD Bq = conv1s_row(g + 1, 0, 0);
    pool_store(A, Bq, g % 21);
  }
  __syncthreads();

  // ---------------- phase 2: O2 ring init a=2..17 ----------------
#pragma unroll
  for (int i = 0; i < 4; ++i) {
    int a = 2 + wid + 4 * i;
    f32x4 acc[4];
#pragma unroll
    for (int ct = 0; ct < 4; ++ct) acc[ct] = bcast4(b2v[ct]);
    conv2_acc(acc, a % 21, 0);
    conv2_acc(acc, (a + 2) % 21, 1);
    conv2_acc(acc, (a + 4) % 21, 2);
    o2_write(acc, a % 17);
  }
  __syncthreads();

  // ---------------- prologue ----------------
  RowD c1A = {};
  // ProA: R0(0)->P23, R0(1)->P24
  if (wid == 0) {
    RowD A = conv1s_row(0, 1, 0), Bq = conv1s_row(1, 0, 0);
    pool_store(A, Bq, 23);
  } else if (wid == 1) {
    RowD A = conv1s_row(1, 1, 0), Bq = conv1s_row(2, 0, 0);
    pool_store(A, Bq, 24);
  }
  __syncthreads();
  // ProB: j0(0)->O2[17], j0(1)->O2[18], R0(4)->P21, R0(5)->P22
  if (wid == 0) {
    f32x4 aj[4];
#pragma unroll
    for (int ct = 0; ct < 4; ++ct) aj[ct] = bcast4(b2v[ct]);
    conv2_acc(aj, 23, 0); conv2_acc(aj, 2, 1); conv2_acc(aj, 4, 2);
    o2_write(aj, 17);
  } else if (wid == 1) {
    f32x4 aj[4];
#pragma unroll
    for (int ct = 0; ct < 4; ++ct) aj[ct] = bcast4(b2v[ct]);
    conv2_acc(aj, 24, 0); conv2_acc(aj, 3, 1); conv2_acc(aj, 5, 2);
    o2_write(aj, 18);
  } else if (wid == 2) {
    RowD A = conv1s_row(4, 1, 0), Bq = conv1s_row(5, 0, 0);
    pool_store(A, Bq, 21);
  } else {
    RowD A = conv1s_row(5, 1, 0), Bq = conv1s_row(6, 0, 0);
    pool_store(A, Bq, 22);
  }
  __syncthreads();
  // ProC: Jpart(0)->Jp[0], Jpart(1)->Jp[1], R0(2)->P23, R0(3)->P24
  if (wid == 0) {
    f32x4 a0 = bcast4(d2bv), a1 = bcast4(0.f);
    dense_jp(17, 2, 0, a0, a1);
    dense_jp(4, 6, 1, a0, a1);
    dense_jp(8, 10, 2, a0, a1);
    dense_jp(12, 14, 3, a0, a1);
    sm.JpartA[0][lane] = a0; sm.JpartB[0][lane] = a1;
  } else if (wid == 1) {
    f32x4 a0 = bcast4(d2bv), a1 = bcast4(0.f);
    dense_jp(18, 3, 0, a0, a1);
    dense_jp(5, 7, 1, a0, a1);
    dense_jp(9, 11, 2, a0, a1);
    dense_jp(13, 15, 3, a0, a1);
    sm.JpartA[1][lane] = a0; sm.JpartB[1][lane] = a1;
  } else if (wid == 2) {
    RowD A = conv1s_row(2, 1, 0), Bq = conv1s_row(3, 0, 0);
    pool_store(A, Bq, 23);
  } else {
    RowD A = conv1s_row(3, 1, 0), Bq = conv1s_row(4, 0, 0);
    pool_store(A, Bq, 24);
  }
  __syncthreads();
  // ProD: j0(2)->O2[19], j0(3)->O2[20], j9 partials(0,1), chain c1A
  if (wid == 0) {
    f32x4 aj[4];
#pragma unroll
    for (int ct = 0; ct < 4; ++ct) aj[ct] = bcast4(b2v[ct]);
    conv2_acc(aj, 23, 0); conv2_acc(aj, 4, 1); conv2_acc(aj, 6, 2);
    o2_write(aj, 19);
  } else if (wid == 1) {
    f32x4 aj[4];
#pragma unroll
    for (int ct = 0; ct < 4; ++ct) aj[ct] = bcast4(b2v[ct]);
    conv2_acc(aj, 24, 0); conv2_acc(aj, 5, 1); conv2_acc(aj, 7, 2);
    o2_write(aj, 20);
  } else if (wid == 2) {
    j9_partial(0, 18);                 // tau=0: pair (0+18)%21 = 18
    j9_partial(1, 19);                 // tau=1: pair 19
  } else {
    c1A = conv1s_row(22, 0, 0);
  }
  __syncthreads();

  if (wid == 3) __builtin_amdgcn_s_setprio(2);

  // ---------------- supersteps: 2 model steps per barrier ----------------
  int tmA21 = 0, tmA17 = 0;     // (2k)%21, (2k)%17
  const int nsup = nt >> 1;     // nt is even (256)
  for (int k = 0; k < nsup; ++k) {
    if (wid == 3) {
#pragma unroll
      for (int d = 0; d < 2; ++d) {
        const int t = 2 * k + d;
        const int sP22 = w21(tmA21 + d + 22);
        const int sO16 = w17(tmA17 + d + 16);
        const int sO18 = w17(tmA17 + d + 18);
        const int sP20 = w21(tmA21 + d + 20);   // pair (t+20): written t-2 = PREV superstep (safe)
        const int h = quad & 1;
        // ---- 1. loop-carried Xcol reads FIRST (DS queue pos 1-3) ----
        uint32_t d22 = sm.Xcol[n][(t + 22) & 31][h];
        uint32_t d23 = sm.Xcol[n][(t + 23) & 31][h];
        uint32_t d24 = sm.Xcol[n][(t + 24) & 31][h];
        // ---- 2. off-chain loads (drain under conv1) ----
        f32x4 jpA = sm.JpartA[t & 3][lane];
        f32x4 jpB = sm.JpartB[t & 3][lane];
        f32x4 pA[4];                            // j9 partial (bias+dw0) from wid2
#pragma unroll
        for (int ct = 0; ct < 4; ++ct) pA[ct] = sm.JA2[t & 3][ct][lane];
        FragU fA20 = ld_P(sP20);
        uint4 qj8[2];
#pragma unroll
        for (int hf = 0; hf < 2; ++hf)
          qj8[hf] = *(const uint4*)&sm.O2[oIdx(sO16, n, (hf * 4 + quad) ^ (n & 7))];
        int li = t; if (li > ntw - 26) li = ntw - 26;
        float lnx = 0.f, lny = 0.f;
        if (n < 4) {
          int veh = quad * 4 + n;
          lnx = sm.leadx[veh][li];
          lny = bf2f(sm.leady[veh][li]);
        }
        // ---- 3. conv1 (consumes only d22..d24 = first 3 returns) ----
        FragU aB, aS;
        aB.q.x = __builtin_amdgcn_perm(d23, d22, 0x05040100u);
        aB.q.y = d24 & 0xffffu;
        aB.q.z = __builtin_amdgcn_perm(d23, d22, 0x07060302u);
        aB.q.w = d24 >> 16;
        aS.q.x = __builtin_amdgcn_perm(d24, d23, 0x05040100u);
        aS.q.y = 0u;
        aS.q.z = __builtin_amdgcn_perm(d24, d23, 0x07060302u);
        aS.q.w = 0u;
        RowD Bq, Sg;
        Bq.d0 = MFMA16(B1[0].v, aB.v, b1q0, 0, 0, 0);
        Bq.d1 = MFMA16(B1[1].v, aB.v, b1q1, 0, 0, 0);
        Sg.d0 = MFMA16(B1[0].v, aS.v, b1q0, 0, 0, 0);
        Sg.d1 = MFMA16(B1[1].v, aS.v, b1q1, 0, 0, 0);
        uint4 w11 = pack4(relumax4(c1A.d0, Bq.d0), relumax4(c1A.d1, Bq.d1));
        uint4 w12 = pack4(relu4(Sg.d0), relu4(Sg.d1));
        p_store(w11, sP22);
        c1A = Bq;
        // ---- 4. finish partials (loads returned during conv1) ----
        f32x4 pB[4];
#pragma unroll
        for (int ct = 0; ct < 4; ++ct) pB[ct] = bcast4(b2v[ct]);
        conv2_accf(pA, fA20, 1);                // j9 += dw1 tap
        conv2_accf(pB, fA20, 0);                // j10 = bias + dw0 tap
        // ---- 5. fresh taps + O2 writes ----
        FragU f11; f11.q = w11;                 // identity: own lane's frag
        FragU f12; f12.q = w12;
        conv2_accf(pA, f11, 2);                 // j9 complete
        conv2_accf(pB, f11, 1);
        conv2_accf(pB, f12, 2);                 // j10 complete
        o2_write(pA, sO18);                     // j9 -> ring
        o2_write(pB, 21);                       // j10 -> scratch 21
        // ---- 6. dense + reduce + state (DS in-order covers write->read) ----
        f32x4 acc2 = bcast4(0.f), acc3 = bcast4(0.f);
        f32x4 acc4 = bcast4(0.f), acc5 = bcast4(0.f);
        dense_jp_pre(sO18, qj8, 4, acc2, acc3);
        dense_jp_pre(21, (const uint4*)nullptr, 5, acc4, acc5);
        float s0 = fmaxf(jpA[0] + jpB[0] + acc2[0] + acc3[0] + acc4[0] + acc5[0], 0.f) * wd1v;
        float s1 = fmaxf(jpA[1] + jpB[1] + acc2[1] + acc3[1] + acc4[1] + acc5[1], 0.f) * wd1v;
        float s2 = fmaxf(jpA[2] + jpB[2] + acc2[2] + acc3[2] + acc4[2] + acc5[2], 0.f) * wd1v;
        float s3 = fmaxf(jpA[3] + jpB[3] + acc2[3] + acc3[3] + acc4[3] + acc5[3], 0.f) * wd1v;
        s0 = rsum16(s0); s1 = rsum16(s1); s2 = rsum16(s2); s3 = rsum16(s3);
        if (n < 4) {
          int veh = quad * 4 + n;
          float sv = (n == 0) ? s0 : (n == 1) ? s1 : (n == 2) ? s2 : s3;
          float accv = 10.f * (sv + bd1v) - 6.f;
          float np_s = pos_s + 0.02f * spd_s;
          float nsp = spd_s * 40.f + 0.1f * accv;
          pos_s = np_s; spd_s = nsp * 0.025f;
          float2 o2v; o2v.x = np_s * 200.f; o2v.y = nsp;
          sm.obuf[(t >> 5) & 1][veh][t & 31] = o2v;
          float x0 = lnx * 0.005f - np_s;
          uint32_t wlo = pkbf(x0, spd_s);
          sm.Xcol[veh][(t + PAST) & 31][0] = wlo;
          sm.Xcol[veh][(t + PAST) & 31][1] = pkbf(lny, x0 - bf2f(wlo & 0xffffu));
        }
      }
    } else if (wid == 0) {
      // Jpart(2k+2), Jpart(2k+3)
#pragma unroll
      for (int e = 0; e < 2; ++e) {
        const int tau = 2 * k + 2 + e;
        f32x4 a0 = bcast4(d2bv), a1 = bcast4(0.f);
        dense_jp(17 + (tau & 3), w17(tmA17 + 4 + e), 0, a0, a1);     // jp0 = max(j0, j1)
        dense_jp(w17(tmA17 + 6 + e), w17(tmA17 + 8 + e), 1, a0, a1);
        dense_jp(w17(tmA17 + 10 + e), w17(tmA17 + 12 + e), 2, a0, a1);
        dense_jp(w17(tmA17 + 14 + e), w17(tmA17 + 16 + e), 3, a0, a1);
        sm.JpartA[tau & 3][lane] = a0;
        sm.JpartB[tau & 3][lane] = a1;
      }
    } else if (wid == 1) {
      // obuf flush (32-step blocks) + j0(2k+4), j0(2k+5)
      if ((k & 15) == 0 && k > 0) {
        int t0 = 2 * k - 32;
        flush_out((t0 >> 5) & 1, t0, 32);
      }
#pragma unroll
      for (int e = 0; e < 2; ++e) {
        const int tau = 2 * k + 4 + e;
        f32x4 aj[4];
#pragma unroll
        for (int ct = 0; ct < 4; ++ct) aj[ct] = bcast4(b2v[ct]);
        conv2_acc(aj, 21 + (tau & 3), 0);                 // R0(tau)
        conv2_acc(aj, w21(tmA21 + 6 + e), 1);             // pair tau+2
        conv2_acc(aj, w21(tmA21 + 8 + e), 2);             // pair tau+4
        o2_write(aj, 17 + (tau & 3));                     // J0[tau&3]
      }
    } else {
      // j9 partials(2k+2, 2k+3) [dw0 only, safe] + row0(2k+6), row0(2k+7)
#pragma unroll
      for (int e = 0; e < 2; ++e) {
        const int tau = 2 * k + 2 + e;
        j9_partial(tau & 3, w21(tmA21 + 20 + e));         // pair tau+18
      }
#pragma unroll
      for (int f = 0; f < 2; ++f) {
        const int tau = 2 * k + 6 + f;
        RowD A = conv1s_row(tau, 1, 0);
        RowD Bq = conv1s_row(tau + 1, 0, 0);
        pool_store(A, Bq, 21 + (tau & 3));
      }
    }
    __syncthreads();
    tmA21 = w21(tmA21 + 2);
    tmA17 = w17(tmA17 + 2);
  }

  // final output flush (steps [nt-32, nt-1])
  if (wid == 1) {
    int t0 = (nt - 1) & ~31;
    flush_out((t0 >> 5) & 1, t0, nt - t0);
  }
}

extern "C" void kernel_launch(void* const* d_in, const int* in_sizes, int n_in,
                              void* d_out, int out_size, void* d_ws, size_t ws_size,
                              hipStream_t stream) {
  const float* lead = (const float*)d_in[0];
  const float* cur  = (const float*)d_in[1];
  // d_in[2] = mask (unused by reference)
  const float* c1w = (const float*)d_in[3];
  const float* c1b = (const float*)d_in[4];
  const float* c2w = (const float*)d_in[5];
  const float* c2b = (const float*)d_in[6];
  const float* d2w = (const float*)d_in[7];
  const float* d2b = (const float*)d_in[8];
  const float* d1w = (const float*)d_in[9];
  const float* d1b = (const float*)d_in[10];
  float* out = (float*)d_out;

  int nveh = in_sizes[1] / (PAST * 2);   // 4096
  int ntw  = in_sizes[2] / nveh;         // nt + PAST - 1 (<= NTW_MAX)
  int nt   = ntw - PAST + 1;             // 256 (even)
  int nblocks = nveh / 16;               // 256 = one per CU

  rnncf_kernel<<<nblocks, 256, 0, stream>>>(lead, cur, c1w, c1b, c2w, c2b,
                                            d2w, d2b, d1w, d1b, out, nt, ntw);
}